// Round 1
// baseline (621.960 us; speedup 1.0000x reference)
//
#include <hip/hip_runtime.h>
#include <math.h>

// Problem constants (fixed by the reference).
#define NU   100000      // N users
#define MI   50000       // M items
#define NEn  150000      // NE = N + M
#define Dd   256         // embedding dim
#define Bp   131072      // batch pairs

// ---------------------------------------------------------------------------
// 64-lane wave reduction (gfx950 wave = 64).
__device__ __forceinline__ float wred(float v) {
#pragma unroll
    for (int m = 32; m > 0; m >>= 1) v += __shfl_xor(v, m, 64);
    return v;
}

// ---------------------------------------------------------------------------
// K1: histogram of entity ids (cnt zeroed by memsetAsync beforehand).
__global__ __launch_bounds__(256) void k_count(const int* __restrict__ x,
                                               int* __restrict__ cnt) {
    int t = blockIdx.x * 256 + threadIdx.x;
    if (t < 2 * Bp) atomicAdd(cnt + x[t], 1);
}

// ---------------------------------------------------------------------------
// K2: per-entity reparameterization + KL.
// One wave per entity row: lane l handles dims [4l, 4l+4) via float4.
// entities_all[e] = mu + |sc| * eps ; klpe[e] = kl_bias(e) + sum_d kl(mu_d, sc_d)
// Rows with cnt==0 are never needed downstream (their KL weight is 0) -> skip.
__global__ __launch_bounds__(256) void k_entity(
    const float4* __restrict__ et,    // entity_table, NE x 2D (row = 128 float4)
    const float4* __restrict__ epse,  // eps_entity,   NE x D  (row = 64 float4)
    const float*  __restrict__ bt,    // bias_table,   NE x 2
    const float*  __restrict__ epsb,  // eps_bias,     NE
    const int*    __restrict__ cnt,
    float4* __restrict__ ent,         // out: entities_all (may be null)
    float*  __restrict__ biases,      // out: biases_all
    float*  __restrict__ klpe)        // out: kl_bias + kl_entity per row
{
    int lane = threadIdx.x & 63;
    int e    = blockIdx.x * 4 + (threadIdx.x >> 6);
    if (cnt[e] == 0) return;  // wave-uniform; no __syncthreads in this kernel

    const float4* row = et + (size_t)e * 128;
    float4 mu = row[lane];
    float4 s4 = row[64 + lane];
    float4 ep = epse[(size_t)e * 64 + lane];
    float scx = fabsf(s4.x), scy = fabsf(s4.y), scz = fabsf(s4.z), scw = fabsf(s4.w);

    if (ent) {
        float4 o;
        o.x = fmaf(scx, ep.x, mu.x);
        o.y = fmaf(scy, ep.y, mu.y);
        o.z = fmaf(scz, ep.z, mu.z);
        o.w = fmaf(scw, ep.w, mu.w);
        ent[(size_t)e * 64 + lane] = o;
    }

    float kl = 0.5f * (scx * scx + mu.x * mu.x - 1.0f) - __logf(scx)
             + 0.5f * (scy * scy + mu.y * mu.y - 1.0f) - __logf(scy)
             + 0.5f * (scz * scz + mu.z * mu.z - 1.0f) - __logf(scz)
             + 0.5f * (scw * scw + mu.w * mu.w - 1.0f) - __logf(scw);
    kl = wred(kl);

    if (lane == 0) {
        float bmu = bt[2 * e];
        float bsc = fabsf(bt[2 * e + 1]);
        biases[e] = fmaf(bsc, epsb[e], bmu);
        klpe[e]   = kl + 0.5f * (bsc * bsc + bmu * bmu - 1.0f) - __logf(bsc);
    }
}

// ---------------------------------------------------------------------------
// K3: user_norm / item_norm = sum cnt/nb_occ over users / items.
// Also seeds out_kl with kl_global (k_klred atomically adds onto it).
__global__ __launch_bounds__(256) void k_norms(
    const int* __restrict__ cnt, const int* __restrict__ nb,
    float* __restrict__ hdr,
    const float* __restrict__ gbm, const float* __restrict__ gbs,
    float* __restrict__ outkl)
{
    int e = blockIdx.x * 256 + threadIdx.x;
    float uv = 0.f, iv = 0.f;
    if (e < NEn) {
        float v = (float)cnt[e] / (float)nb[e];
        if (e < NU) uv = v; else iv = v;
    }
    uv = wred(uv);
    iv = wred(iv);
    if ((threadIdx.x & 63) == 0) {
        if (uv != 0.f) atomicAdd(hdr + 0, uv);
        if (iv != 0.f) atomicAdd(hdr + 1, iv);
    }
    if (blockIdx.x == 0 && threadIdx.x == 0) {
        float gm = gbm[0];
        float gs = fabsf(gbs[0]);
        outkl[0] = 0.5f * (gs * gs + gm * gm - 1.0f) - __logf(gs);
    }
}

// ---------------------------------------------------------------------------
// K4a: logits via precomputed entities_all (fast path).
// One wave per pair; lane l loads float4 from each row -> 1KB coalesced/row.
__global__ __launch_bounds__(256) void k_logits(
    const int* __restrict__ x, const float4* __restrict__ ent,
    const float* __restrict__ biases,
    const float* __restrict__ gbm, const float* __restrict__ gbs,
    const float* __restrict__ epsg, float* __restrict__ out)
{
    int lane = threadIdx.x & 63;
    int p    = blockIdx.x * 4 + (threadIdx.x >> 6);
    int u = x[2 * p], v = x[2 * p + 1];
    float4 a = ent[(size_t)u * 64 + lane];
    float4 b = ent[(size_t)v * 64 + lane];
    float d = a.x * b.x + a.y * b.y + a.z * b.z + a.w * b.w;
    d = wred(d);
    if (lane == 0) {
        float gb = fmaf(fabsf(gbs[0]), epsg[0], gbm[0]);
        out[p] = gb + biases[u] + biases[v] + d;
    }
}

// K4b: fallback — recompute reparameterized rows in the gather (ws too small).
__global__ __launch_bounds__(256) void k_logits_rc(
    const int* __restrict__ x, const float4* __restrict__ et,
    const float4* __restrict__ epse, const float* __restrict__ biases,
    const float* __restrict__ gbm, const float* __restrict__ gbs,
    const float* __restrict__ epsg, float* __restrict__ out)
{
    int lane = threadIdx.x & 63;
    int p    = blockIdx.x * 4 + (threadIdx.x >> 6);
    int u = x[2 * p], v = x[2 * p + 1];
    const float4* ru = et + (size_t)u * 128;
    const float4* rv = et + (size_t)v * 128;
    float4 mu_u = ru[lane], s_u = ru[64 + lane], e_u = epse[(size_t)u * 64 + lane];
    float4 mu_v = rv[lane], s_v = rv[64 + lane], e_v = epse[(size_t)v * 64 + lane];
    float ax = fmaf(fabsf(s_u.x), e_u.x, mu_u.x), bx = fmaf(fabsf(s_v.x), e_v.x, mu_v.x);
    float ay = fmaf(fabsf(s_u.y), e_u.y, mu_u.y), by = fmaf(fabsf(s_v.y), e_v.y, mu_v.y);
    float az = fmaf(fabsf(s_u.z), e_u.z, mu_u.z), bz = fmaf(fabsf(s_v.z), e_v.z, mu_v.z);
    float aw = fmaf(fabsf(s_u.w), e_u.w, mu_u.w), bw = fmaf(fabsf(s_v.w), e_v.w, mu_v.w);
    float d = ax * bx + ay * by + az * bz + aw * bw;
    d = wred(d);
    if (lane == 0) {
        float gb = fmaf(fabsf(gbs[0]), epsg[0], gbm[0]);
        out[p] = gb + biases[u] + biases[v] + d;
    }
}

// ---------------------------------------------------------------------------
// K5: kl_rescaled = sum_e klpe[e] * (cnt/nb_occ) * scale_term(e), atomic into out[B].
// scale_term: ids <= N -> N/user_norm (NOTE: inclusive, matches reference);
//             ids >  N -> M/item_norm.
__global__ __launch_bounds__(256) void k_klred(
    const float* __restrict__ klpe, const int* __restrict__ cnt,
    const int* __restrict__ nb, const float* __restrict__ hdr,
    float* __restrict__ outkl)
{
    int e = blockIdx.x * 256 + threadIdx.x;
    float t = 0.f;
    if (e < NEn) {
        int c = cnt[e];
        if (c != 0) {
            float sc = (e <= NU) ? ((float)NU / hdr[0]) : ((float)MI / hdr[1]);
            t = klpe[e] * ((float)c / (float)nb[e]) * sc;
        }
    }
    t = wred(t);
    if ((threadIdx.x & 63) == 0 && t != 0.f) atomicAdd(outkl, t);
}

// ---------------------------------------------------------------------------
extern "C" void kernel_launch(void* const* d_in, const int* in_sizes, int n_in,
                              void* d_out, int out_size, void* d_ws, size_t ws_size,
                              hipStream_t stream)
{
    const int*   x    = (const int*)d_in[0];
    const float* bt   = (const float*)d_in[1];
    const float* et   = (const float*)d_in[2];
    const float* gbm  = (const float*)d_in[3];
    const float* gbs  = (const float*)d_in[4];
    const int*   nb   = (const int*)d_in[5];
    const float* epsb = (const float*)d_in[6];
    const float* epse = (const float*)d_in[7];
    const float* epsg = (const float*)d_in[8];
    float* out = (float*)d_out;   // [0..B) logits, [B] KL scalar

    char*  ws   = (char*)d_ws;
    float* hdr  = (float*)ws;                              // hdr[0]=user_norm hdr[1]=item_norm
    int*   cnt  = (int*)  (ws + 64);                       // NE ints
    float* klpe = (float*)(ws + 64 + (size_t)NEn * 4);     // NE floats
    float* bia  = (float*)(ws + 64 + (size_t)NEn * 8);     // NE floats
    size_t entoff = 64 + (size_t)NEn * 12;
    float4* ent = nullptr;
    if (ws_size >= entoff + (size_t)NEn * Dd * 4)          // ~155.4 MB total
        ent = (float4*)(ws + entoff);

    // ws is re-poisoned to 0xAA before every timed call: zero hdr + cnt each time.
    hipMemsetAsync(ws, 0, 64 + (size_t)NEn * 4, stream);

    k_count <<<(2 * Bp + 255) / 256, 256, 0, stream>>>(x, cnt);
    k_entity<<<NEn / 4,              256, 0, stream>>>((const float4*)et,
                                                       (const float4*)epse,
                                                       bt, epsb, cnt, ent, bia, klpe);
    k_norms <<<(NEn + 255) / 256,    256, 0, stream>>>(cnt, nb, hdr, gbm, gbs, out + Bp);
    if (ent)
        k_logits   <<<Bp / 4, 256, 0, stream>>>(x, ent, bia, gbm, gbs, epsg, out);
    else
        k_logits_rc<<<Bp / 4, 256, 0, stream>>>(x, (const float4*)et,
                                                (const float4*)epse, bia,
                                                gbm, gbs, epsg, out);
    k_klred <<<(NEn + 255) / 256,    256, 0, stream>>>(klpe, cnt, nb, hdr, out + Bp);
}

// Round 3
// 603.893 us; speedup vs baseline: 1.0299x; 1.0299x over previous
//
#include <hip/hip_runtime.h>
#include <math.h>

// Problem constants (fixed by the reference).
#define NU   100000      // N users
#define MI   50000       // M items
#define NEn  150000      // NE = N + M
#define Bp   131072      // batch pairs

// Native vector type for nontemporal builtins (HIP float4 is a struct and
// __builtin_nontemporal_load rejects it).
typedef float f4v __attribute__((ext_vector_type(4)));

// ---------------------------------------------------------------------------
// 64-lane wave reduction (gfx950 wave = 64).
__device__ __forceinline__ float wred(float v) {
#pragma unroll
    for (int m = 32; m > 0; m >>= 1) v += __shfl_xor(v, m, 64);
    return v;
}

// ---------------------------------------------------------------------------
// K1: histogram of entity ids (cnt zeroed by memsetAsync beforehand).
// Thread 0 also seeds out[B] with kl_global (k_klred atomically adds onto it).
__global__ __launch_bounds__(256) void k_count(const int* __restrict__ x,
                                               int* __restrict__ cnt,
                                               const float* __restrict__ gbm,
                                               const float* __restrict__ gbs,
                                               float* __restrict__ outkl) {
    int t = blockIdx.x * 256 + threadIdx.x;
    if (t < 2 * Bp) atomicAdd(cnt + x[t], 1);
    if (t == 0) {
        float gm = gbm[0];
        float gs = fabsf(gbs[0]);
        outkl[0] = 0.5f * (gs * gs + gm * gm - 1.0f) - __logf(gs);
    }
}

// ---------------------------------------------------------------------------
// K2: per-entity reparameterization + KL. One wave per entity row.
// Streaming inputs (et, epse) read NONTEMPORAL so the ent output stays
// L3-resident for k_logits' gathers. Rows with cnt==0 skipped (KL weight 0,
// never gathered).
__global__ __launch_bounds__(256) void k_entity(
    const f4v* __restrict__ et,       // entity_table, NE x 2D (row = 128 float4)
    const f4v* __restrict__ epse,     // eps_entity,   NE x D  (row = 64 float4)
    const float* __restrict__ bt,     // bias_table,   NE x 2
    const float* __restrict__ epsb,   // eps_bias,     NE
    const int*   __restrict__ cnt,
    f4v*   __restrict__ ent,          // out: entities_all (may be null)
    float* __restrict__ biases,       // out: biases_all
    float* __restrict__ klpe)         // out: kl_bias + kl_entity per row
{
    int lane = threadIdx.x & 63;
    int e    = blockIdx.x * 4 + (threadIdx.x >> 6);
    if (cnt[e] == 0) return;  // wave-uniform

    const f4v* row = et + (size_t)e * 128;
    f4v mu = __builtin_nontemporal_load(row + lane);
    f4v s4 = __builtin_nontemporal_load(row + 64 + lane);
    f4v ep = __builtin_nontemporal_load(epse + (size_t)e * 64 + lane);
    float scx = fabsf(s4.x), scy = fabsf(s4.y), scz = fabsf(s4.z), scw = fabsf(s4.w);

    if (ent) {
        f4v o;
        o.x = fmaf(scx, ep.x, mu.x);
        o.y = fmaf(scy, ep.y, mu.y);
        o.z = fmaf(scz, ep.z, mu.z);
        o.w = fmaf(scw, ep.w, mu.w);
        ent[(size_t)e * 64 + lane] = o;   // temporal: want this L3-resident
    }

    float kl = 0.5f * (scx * scx + mu.x * mu.x - 1.0f) - __logf(scx)
             + 0.5f * (scy * scy + mu.y * mu.y - 1.0f) - __logf(scy)
             + 0.5f * (scz * scz + mu.z * mu.z - 1.0f) - __logf(scz)
             + 0.5f * (scw * scw + mu.w * mu.w - 1.0f) - __logf(scw);
    kl = wred(kl);

    if (lane == 0) {
        float bmu = bt[2 * e];
        float bsc = fabsf(bt[2 * e + 1]);
        biases[e] = fmaf(bsc, epsb[e], bmu);
        klpe[e]   = kl + 0.5f * (bsc * bsc + bmu * bmu - 1.0f) - __logf(bsc);
    }
}

// ---------------------------------------------------------------------------
// K3: user_norm / item_norm = sum cnt/nb_occ over users / items.
__global__ __launch_bounds__(256) void k_norms(
    const int* __restrict__ cnt, const int* __restrict__ nb,
    float* __restrict__ hdr)
{
    int e = blockIdx.x * 256 + threadIdx.x;
    float uv = 0.f, iv = 0.f;
    if (e < NEn) {
        float v = (float)cnt[e] / (float)nb[e];
        if (e < NU) uv = v; else iv = v;
    }
    uv = wred(uv);
    iv = wred(iv);
    if ((threadIdx.x & 63) == 0) {
        if (uv != 0.f) atomicAdd(hdr + 0, uv);
        if (iv != 0.f) atomicAdd(hdr + 1, iv);
    }
}

// ---------------------------------------------------------------------------
// K4a: logits via precomputed entities_all (fast path, ent mostly L3-hit).
__global__ __launch_bounds__(256) void k_logits(
    const int* __restrict__ x, const float4* __restrict__ ent,
    const float* __restrict__ biases,
    const float* __restrict__ gbm, const float* __restrict__ gbs,
    const float* __restrict__ epsg, float* __restrict__ out)
{
    int lane = threadIdx.x & 63;
    int p    = blockIdx.x * 4 + (threadIdx.x >> 6);
    int u = x[2 * p], v = x[2 * p + 1];
    float4 a = ent[(size_t)u * 64 + lane];
    float4 b = ent[(size_t)v * 64 + lane];
    float d = a.x * b.x + a.y * b.y + a.z * b.z + a.w * b.w;
    d = wred(d);
    if (lane == 0) {
        float gb = fmaf(fabsf(gbs[0]), epsg[0], gbm[0]);
        out[p] = gb + biases[u] + biases[v] + d;
    }
}

// K4b: fallback — recompute reparameterized rows in the gather (ws too small).
__global__ __launch_bounds__(256) void k_logits_rc(
    const int* __restrict__ x, const float4* __restrict__ et,
    const float4* __restrict__ epse, const float* __restrict__ biases,
    const float* __restrict__ gbm, const float* __restrict__ gbs,
    const float* __restrict__ epsg, float* __restrict__ out)
{
    int lane = threadIdx.x & 63;
    int p    = blockIdx.x * 4 + (threadIdx.x >> 6);
    int u = x[2 * p], v = x[2 * p + 1];
    const float4* ru = et + (size_t)u * 128;
    const float4* rv = et + (size_t)v * 128;
    float4 mu_u = ru[lane], s_u = ru[64 + lane], e_u = epse[(size_t)u * 64 + lane];
    float4 mu_v = rv[lane], s_v = rv[64 + lane], e_v = epse[(size_t)v * 64 + lane];
    float ax = fmaf(fabsf(s_u.x), e_u.x, mu_u.x), bx = fmaf(fabsf(s_v.x), e_v.x, mu_v.x);
    float ay = fmaf(fabsf(s_u.y), e_u.y, mu_u.y), by = fmaf(fabsf(s_v.y), e_v.y, mu_v.y);
    float az = fmaf(fabsf(s_u.z), e_u.z, mu_u.z), bz = fmaf(fabsf(s_v.z), e_v.z, mu_v.z);
    float aw = fmaf(fabsf(s_u.w), e_u.w, mu_u.w), bw = fmaf(fabsf(s_v.w), e_v.w, mu_v.w);
    float d = ax * bx + ay * by + az * bz + aw * bw;
    d = wred(d);
    if (lane == 0) {
        float gb = fmaf(fabsf(gbs[0]), epsg[0], gbm[0]);
        out[p] = gb + biases[u] + biases[v] + d;
    }
}

// ---------------------------------------------------------------------------
// K5: kl_rescaled = sum_e klpe[e] * (cnt/nb_occ) * scale_term(e) -> atomic out[B].
// scale_term: ids <= N (INCLUSIVE, reference quirk) -> N/user_norm; else M/item_norm.
__global__ __launch_bounds__(256) void k_klred(
    const float* __restrict__ klpe, const int* __restrict__ cnt,
    const int* __restrict__ nb, const float* __restrict__ hdr,
    float* __restrict__ outkl)
{
    int e = blockIdx.x * 256 + threadIdx.x;
    float t = 0.f;
    if (e < NEn) {
        int c = cnt[e];
        if (c != 0) {
            float sc = (e <= NU) ? ((float)NU / hdr[0]) : ((float)MI / hdr[1]);
            t = klpe[e] * ((float)c / (float)nb[e]) * sc;
        }
    }
    t = wred(t);
    if ((threadIdx.x & 63) == 0 && t != 0.f) atomicAdd(outkl, t);
}

// ---------------------------------------------------------------------------
extern "C" void kernel_launch(void* const* d_in, const int* in_sizes, int n_in,
                              void* d_out, int out_size, void* d_ws, size_t ws_size,
                              hipStream_t stream)
{
    const int*   x    = (const int*)d_in[0];
    const float* bt   = (const float*)d_in[1];
    const float* et   = (const float*)d_in[2];
    const float* gbm  = (const float*)d_in[3];
    const float* gbs  = (const float*)d_in[4];
    const int*   nb   = (const int*)d_in[5];
    const float* epsb = (const float*)d_in[6];
    const float* epse = (const float*)d_in[7];
    const float* epsg = (const float*)d_in[8];
    float* out = (float*)d_out;   // [0..B) logits, [B] KL scalar

    char*  ws   = (char*)d_ws;
    float* hdr  = (float*)ws;                              // hdr[0]=user_norm hdr[1]=item_norm
    int*   cnt  = (int*)  (ws + 64);                       // NE ints
    float* klpe = (float*)(ws + 64 + (size_t)NEn * 4);     // NE floats
    float* bia  = (float*)(ws + 64 + (size_t)NEn * 8);     // NE floats
    size_t entoff = 64 + (size_t)NEn * 12;
    float4* ent = nullptr;
    if (ws_size >= entoff + (size_t)NEn * 256 * 4)         // ~155.4 MB total
        ent = (float4*)(ws + entoff);

    // ws is re-poisoned to 0xAA before every timed call: zero hdr + cnt each time.
    (void)hipMemsetAsync(ws, 0, 64 + (size_t)NEn * 4, stream);

    k_count <<<(2 * Bp + 255) / 256, 256, 0, stream>>>(x, cnt, gbm, gbs, out + Bp);
    k_entity<<<NEn / 4,              256, 0, stream>>>((const f4v*)et,
                                                       (const f4v*)epse,
                                                       bt, epsb, cnt, (f4v*)ent, bia, klpe);
    k_norms <<<(NEn + 255) / 256,    256, 0, stream>>>(cnt, nb, hdr);
    if (ent)
        k_logits   <<<Bp / 4, 256, 0, stream>>>(x, ent, bia, gbm, gbs, epsg, out);
    else
        k_logits_rc<<<Bp / 4, 256, 0, stream>>>(x, (const float4*)et,
                                                (const float4*)epse, bia,
                                                gbm, gbs, epsg, out);
    k_klred <<<(NEn + 255) / 256,    256, 0, stream>>>(klpe, cnt, nb, hdr, out + Bp);
}